// Round 12
// baseline (297.609 us; speedup 1.0000x reference)
//
#include <hip/hip_runtime.h>
#include <hip/hip_bf16.h>
#include <hip/hip_fp16.h>

// SparseGAT forward. Swapped-operand fp16 MFMA feature transform (direct
// register->global stores); CSR edge pipeline, 16-lane-group rows,
// degree-sorted HEAVY-FIRST; fused CSR-build kernels (9 dispatches total).
// N=50000, FI=256, FO=64, H=8, E=800000, avg deg 16.
//
// Th [n][h*64+f] head-major fp16 (1KB/row).
// ws: Th[N*512]f16 | Wth[8*64*256]f16 | aw[N*8]f32 | deg[N] | blockhist[64*nbp]
//     | row_start[N+4] | cursor[N] | colperm[E] | blocksums[64] | row_order[N]

#define FI 256
#define FO 64
#define NH 8
#define FC 512
#define BM 128
#define NBIN 64

typedef _Float16 f16x8 __attribute__((ext_vector_type(8)));
typedef float f32x16 __attribute__((ext_vector_type(16)));
typedef float f32x8 __attribute__((ext_vector_type(8)));

// ---------------- P1: W[h][k][f] -> Wth[h][f][k] fp16 -----------------------
__global__ __launch_bounds__(256)
void p1_wconv(const float* __restrict__ W, _Float16* __restrict__ Wth) {
  int idx = blockIdx.x * 256 + threadIdx.x;   // h*64*256 + f*256 + k
  if (idx >= NH * FO * FI) return;
  int k = idx & (FI - 1);
  int f = (idx >> 8) & (FO - 1);
  int h = idx >> 14;
  Wth[idx] = (_Float16)W[((size_t)h * FI + k) * FO + f];
}

// ---------------- K1v3: swapped-operand MFMA, direct stores ------------------
__global__ __launch_bounds__(512)
void k1_v3(const float* __restrict__ x, const _Float16* __restrict__ Wth,
           const float* __restrict__ a, _Float16* __restrict__ Th,
           float* __restrict__ aw, int N) {
  __shared__ _Float16 Xs[BM][136];   // 34.8 KB; +8 pad
  const int bm = blockIdx.x * BM;
  const int t = threadIdx.x;
  const int w = t >> 6;             // wave id = head
  const int lane = t & 63;
  const int l31 = lane & 31;
  const int hi = lane >> 5;
  const int kh = hi * 8;
  const _Float16* Wh = Wth + (size_t)w * (FO * FI);

  f32x16 acc[4][2];
  #pragma unroll
  for (int mr = 0; mr < 4; ++mr)
    #pragma unroll
    for (int wc = 0; wc < 2; ++wc) acc[mr][wc] = (f32x16)0.0f;

  #pragma unroll
  for (int k0 = 0; k0 < 2; ++k0) {
    if (k0) __syncthreads();
    #pragma unroll
    for (int r = 0; r < 8; ++r) {
      int i = t + r * 512;          // 0..4095
      int row = i >> 5;             // 32 float4 per row
      int q = i & 31;
      float4 v = make_float4(0.f, 0.f, 0.f, 0.f);
      if (bm + row < N)
        v = reinterpret_cast<const float4*>(&x[(size_t)(bm + row) * FI + k0 * 128])[q];
      _Float16 o[4] = {(_Float16)v.x, (_Float16)v.y, (_Float16)v.z, (_Float16)v.w};
      *reinterpret_cast<uint2*>(&Xs[row][q * 4]) = *reinterpret_cast<uint2*>(o);
    }
    __syncthreads();
    #pragma unroll
    for (int kk = 0; kk < 8; ++kk) {
      f16x8 xf[4], wf[2];
      #pragma unroll
      for (int mr = 0; mr < 4; ++mr)
        xf[mr] = *reinterpret_cast<const f16x8*>(&Xs[mr * 32 + l31][kk * 16 + kh]);
      #pragma unroll
      for (int wc = 0; wc < 2; ++wc)
        wf[wc] = *reinterpret_cast<const f16x8*>(
            &Wh[(size_t)(wc * 32 + l31) * FI + k0 * 128 + kk * 16 + kh]);
      // SWAPPED: A=W-frag (i=f), B=x-frag (j=node) -> D[f][node]
      #pragma unroll
      for (int mr = 0; mr < 4; ++mr)
        #pragma unroll
        for (int wc = 0; wc < 2; ++wc)
          acc[mr][wc] =
              __builtin_amdgcn_mfma_f32_32x32x16_f16(wf[wc], xf[mr], acc[mr][wc], 0, 0, 0);
    }
  }

  // aw: per-lane dot over its 32 f, combine lane-halves with one shfl
  float s4[4] = {0.f, 0.f, 0.f, 0.f};
  #pragma unroll
  for (int wc = 0; wc < 2; ++wc)
    #pragma unroll
    for (int reg = 0; reg < 16; ++reg) {
      float av = a[w * FO + wc * 32 + (reg & 3) + 8 * (reg >> 2) + 4 * hi];
      #pragma unroll
      for (int mr = 0; mr < 4; ++mr)
        s4[mr] = fmaf(acc[mr][wc][reg], av, s4[mr]);
    }
  #pragma unroll
  for (int mr = 0; mr < 4; ++mr) {
    float s = s4[mr] + __shfl_xor(s4[mr], 32);
    int n = bm + mr * 32 + l31;
    if (hi == 0 && n < N) aw[(size_t)n * NH + w] = s;
  }

  // direct stores: per (mr,wc,quad g): 4 consecutive f -> 8B store
  #pragma unroll
  for (int mr = 0; mr < 4; ++mr) {
    int n = bm + mr * 32 + l31;
    if (n >= N) continue;
    _Float16* rowp = Th + (size_t)n * FC + w * FO;
    #pragma unroll
    for (int wc = 0; wc < 2; ++wc)
      #pragma unroll
      for (int g = 0; g < 4; ++g) {
        _Float16 o[4] = {(_Float16)acc[mr][wc][4 * g + 0],
                         (_Float16)acc[mr][wc][4 * g + 1],
                         (_Float16)acc[mr][wc][4 * g + 2],
                         (_Float16)acc[mr][wc][4 * g + 3]};
        *reinterpret_cast<uint2*>(&rowp[wc * 32 + 8 * g + 4 * hi]) =
            *reinterpret_cast<uint2*>(o);
      }
  }
}

// ---------------- B1: degree histogram --------------------------------------
__global__ __launch_bounds__(256)
void b1_hist(const int* __restrict__ rows, int* __restrict__ deg, int E) {
  int e = blockIdx.x * 256 + threadIdx.x;
  if (e < E) atomicAdd(&deg[rows[e]], 1);
}

// ---------------- B2a: per-block sums + per-block degree histogram ----------
__global__ __launch_bounds__(256)
void b2a_blocksum(const int* __restrict__ deg, int* __restrict__ blocksums,
                  int* __restrict__ blockhist, int N, int nbp) {
  __shared__ int red[256];
  __shared__ int hist[NBIN];
  const int t = threadIdx.x;
  const int base = blockIdx.x * 1024 + t * 4;
  if (t < NBIN) hist[t] = 0;
  int v[4]; int s = 0;
  #pragma unroll
  for (int j = 0; j < 4; ++j) { int i = base + j; v[j] = (i < N) ? deg[i] : 0; s += v[j]; }
  __syncthreads();                      // hist init visible
  #pragma unroll
  for (int j = 0; j < 4; ++j)
    if (base + j < N) atomicAdd(&hist[min(v[j], NBIN - 1)], 1);
  red[t] = s;
  __syncthreads();
  for (int off = 128; off; off >>= 1) {
    if (t < off) red[t] += red[t + off];
    __syncthreads();
  }
  if (t == 0) blocksums[blockIdx.x] = red[0];
  if (t < NBIN) blockhist[t * nbp + blockIdx.x] = hist[t];
}

// ---------------- B2b5b: fused single-wave scans (128 threads) --------------
// wave 0: exclusive scan of blocksums. wave 1: bin offsets, HEAVY-FIRST
// (bin 63 gets global base 0).
__global__ __launch_bounds__(128)
void b2b5b_scan(int* __restrict__ blocksums, int nb,
                int* __restrict__ row_start, int N, int E,
                int* __restrict__ blockhist, int nbp) {
  const int w = threadIdx.x >> 6;
  const int lane = threadIdx.x & 63;
  if (w == 0) {
    int carry = 0;
    for (int base = 0; base < nb; base += 64) {
      int i = base + lane;
      int v = (i < nb) ? blocksums[i] : 0;
      int inc = v;
      #pragma unroll
      for (int off = 1; off < 64; off <<= 1) {
        int t = __shfl_up(inc, off);
        if (lane >= off) inc += t;
      }
      if (i < nb) blocksums[i] = inc - v + carry;  // exclusive
      carry += __shfl(inc, 63);
    }
    if (lane == 0) row_start[N] = E;
  } else {
    // lane handles bin (63 - lane): descending-degree global order
    int* rowp = blockhist + (size_t)(NBIN - 1 - lane) * nbp;
    int tot = 0;
    for (int c = 0; c < nbp / 4; ++c) {
      int4 v = reinterpret_cast<const int4*>(rowp)[c];
      tot += v.x + v.y + v.z + v.w;
    }
    int inc = tot;
    #pragma unroll
    for (int off = 1; off < 64; off <<= 1) {
      int t = __shfl_up(inc, off);
      if (lane >= off) inc += t;
    }
    int run = inc - tot;              // global base of this bin
    for (int c = 0; c < nbp / 4; ++c) {
      int4 v = reinterpret_cast<const int4*>(rowp)[c];
      int4 o;
      o.x = run; run += v.x;
      o.y = run; run += v.y;
      o.z = run; run += v.z;
      o.w = run; run += v.w;
      reinterpret_cast<int4*>(rowp)[c] = o;
    }
  }
}

// ---------------- B2c: per-block rescan -> row_start, cursor ----------------
__global__ __launch_bounds__(256)
void b2c_rescan(const int* __restrict__ deg, const int* __restrict__ blocksums,
                int* __restrict__ row_start, int* __restrict__ cursor, int N) {
  __shared__ int ts[256];
  const int t = threadIdx.x;
  const int base = blockIdx.x * 1024 + t * 4;
  int v[4]; int s = 0;
  #pragma unroll
  for (int j = 0; j < 4; ++j) { int i = base + j; v[j] = (i < N) ? deg[i] : 0; s += v[j]; }
  ts[t] = s;
  __syncthreads();
  for (int off = 1; off < 256; off <<= 1) {
    int add = (t >= off) ? ts[t - off] : 0;
    __syncthreads();
    ts[t] += add;
    __syncthreads();
  }
  int run = blocksums[blockIdx.x] + ts[t] - s;
  #pragma unroll
  for (int j = 0; j < 4; ++j) {
    int i = base + j;
    if (i < N) { row_start[i] = run; cursor[i] = run; run += v[j]; }
  }
}

// ---------------- B3+B5c fused: edge scatter + row-order scatter ------------
// blocks [0, nb): b5c row scatter (LDS cursors). blocks [nb, ..): b3 edges.
__global__ __launch_bounds__(256)
void b3b5c_scatter(const int* __restrict__ rows, const int* __restrict__ cols,
                   int* __restrict__ cursor, int* __restrict__ colperm, int E,
                   const int* __restrict__ deg, const int* __restrict__ blockhist,
                   int* __restrict__ row_order, int N, int nbp, int nb) {
  __shared__ int cur[NBIN];
  const int t = threadIdx.x;
  if ((int)blockIdx.x < nb) {
    if (t < NBIN) cur[t] = blockhist[t * nbp + blockIdx.x];
    __syncthreads();
    const int base = blockIdx.x * 1024 + t * 4;
    #pragma unroll
    for (int j = 0; j < 4; ++j) {
      int i = base + j;
      if (i < N) {
        int pos = atomicAdd(&cur[min(deg[i], NBIN - 1)], 1);
        row_order[pos] = i;
      }
    }
  } else {
    int e = (blockIdx.x - nb) * 256 + t;
    if (e < E) {
      int pos = atomicAdd(&cursor[rows[e]], 1);
      colperm[pos] = cols[e];
    }
  }
}

// ---------------- K4: fused softmax + aggregation, head-major Th ------------
__global__ __launch_bounds__(256)
void k4_fused(const int* __restrict__ row_start, const int* __restrict__ colperm,
              const int* __restrict__ row_order,
              const float* __restrict__ aw, const _Float16* __restrict__ Th,
              const float* __restrict__ b, float* __restrict__ out, int N) {
  const int lane16 = threadIdx.x & 15;
  const int gbase  = threadIdx.x & 48;       // group base lane within wave
  const int hi8    = lane16 >> 3;            // head parity of this lane
  const int ri = blockIdx.x * 16 + (threadIdx.x >> 4);
  if (ri >= N) return;
  const int r = row_order[ri];

  const int s0 = row_start[r], s1 = row_start[r + 1];
  f32x8 awr = *reinterpret_cast<const f32x8*>(&aw[(size_t)r * NH]);

  float facc[4][8] = {};
  float dacc[NH] = {};

  for (int base = s0; base < s1; base += 16) {
    const int mm = min(16, s1 - base);
    const bool valid = lane16 < mm;
    int c_l = valid ? colperm[base + lane16] : 0;

    f32x8 awc = *reinterpret_cast<const f32x8*>(&aw[(size_t)c_l * NH]);
    float ex[NH];
    int pkv[4];
    #pragma unroll
    for (int h = 0; h < NH; ++h) {
      float s = awr[h] + awc[h];
      float lr = s > 0.f ? s : 0.2f * s;
      ex[h] = valid ? __expf(lr) : 0.f;
      dacc[h] += ex[h];
    }
    #pragma unroll
    for (int q = 0; q < 4; ++q) {
      __half2 h2 = __floats2half2_rn(ex[2 * q], ex[2 * q + 1]);
      pkv[q] = *reinterpret_cast<int*>(&h2);
    }

    for (int j = 0; j < mm; ++j) {
      int cj = __shfl(c_l, gbase + j);
      const _Float16* tp = Th + (size_t)cj * FC + lane16 * 8;
      f16x8 tv0 = *reinterpret_cast<const f16x8*>(tp);
      f16x8 tv1 = *reinterpret_cast<const f16x8*>(tp + 128);
      f16x8 tv2 = *reinterpret_cast<const f16x8*>(tp + 256);
      f16x8 tv3 = *reinterpret_cast<const f16x8*>(tp + 384);
      float eq[4];
      #pragma unroll
      for (int q = 0; q < 4; ++q) {
        int p = __shfl(pkv[q], gbase + j);
        float2 f2 = __half22float2(*reinterpret_cast<__half2*>(&p));
        eq[q] = hi8 ? f2.y : f2.x;
      }
      #pragma unroll
      for (int e = 0; e < 8; ++e) {
        facc[0][e] = fmaf(eq[0], (float)tv0[e], facc[0][e]);
        facc[1][e] = fmaf(eq[1], (float)tv1[e], facc[1][e]);
        facc[2][e] = fmaf(eq[2], (float)tv2[e], facc[2][e]);
        facc[3][e] = fmaf(eq[3], (float)tv3[e], facc[3][e]);
      }
    }
  }

  #pragma unroll
  for (int h = 0; h < NH; ++h) {
    #pragma unroll
    for (int off = 1; off < 16; off <<= 1)
      dacc[h] += __shfl_xor(dacc[h], off);
  }
  float rden[NH];
  #pragma unroll
  for (int h = 0; h < NH; ++h) rden[h] = dacc[h] > 0.f ? 1.0f / dacc[h] : 0.f;

  float s[8] = {};
  #pragma unroll
  for (int q = 0; q < 4; ++q) {
    float rd = hi8 ? rden[2 * q + 1] : rden[2 * q];
    #pragma unroll
    for (int e = 0; e < 8; ++e) s[e] = fmaf(facc[q][e], rd, s[e]);
  }
  #pragma unroll
  for (int e = 0; e < 8; ++e) s[e] += __shfl_xor(s[e], 8);

  if (lane16 < 8) {
    #pragma unroll
    for (int e = 0; e < 8; ++e) {
      const int f = lane16 * 8 + e;
      float sb = 0.f;
      #pragma unroll
      for (int h = 0; h < NH; ++h) sb += b[h * FO + f];
      float v = (s[e] + sb) * 0.125f;
      out[(size_t)r * FO + f] = v > 0.f ? v : 0.f;
    }
  }
}

extern "C" void kernel_launch(void* const* d_in, const int* in_sizes, int n_in,
                              void* d_out, int out_size, void* d_ws, size_t ws_size,
                              hipStream_t stream) {
  const float* x    = (const float*)d_in[0];
  const float* W    = (const float*)d_in[1];
  const float* a    = (const float*)d_in[2];
  const float* b    = (const float*)d_in[3];
  const int*   rows = (const int*)d_in[4];
  const int*   cols = (const int*)d_in[5];
  const int N = in_sizes[0] / FI;
  const int E = in_sizes[4];

  const int nb  = (N + 1023) / 1024;        // 1024-row blocks
  const int nbp = ((nb + 3) / 4) * 4;       // padded for int4 in b5b

  char* p = (char*)d_ws;
  _Float16* Th       = (_Float16*)p;  p += (size_t)N * FC * sizeof(_Float16);
  _Float16* Wth      = (_Float16*)p;  p += (size_t)NH * FO * FI * sizeof(_Float16);
  float*    aw       = (float*)p;     p += (size_t)N * NH * sizeof(float);
  int*      deg      = (int*)p;       p += (size_t)N * sizeof(int);
  int*      blockhist= (int*)p;       p += (size_t)NBIN * nbp * sizeof(int);
  int*      row_start= (int*)p;       p += (size_t)(N + 4) * sizeof(int);
  int*      cursor   = (int*)p;       p += (size_t)N * sizeof(int);
  int*      colperm  = (int*)p;       p += (size_t)E * sizeof(int);
  int*      blocksums= (int*)p;       p += 64 * sizeof(int);
  int*      row_order= (int*)p;       p += (size_t)N * sizeof(int);
  float*    out = (float*)d_out;

  // CSR build + degree sort (deg and blockhist adjacent: one memset)
  hipMemsetAsync(deg, 0, ((size_t)N + (size_t)NBIN * nbp) * sizeof(int), stream);
  b1_hist<<<(E + 255) / 256, 256, 0, stream>>>(rows, deg, E);
  b2a_blocksum<<<nb, 256, 0, stream>>>(deg, blocksums, blockhist, N, nbp);
  b2b5b_scan<<<1, 128, 0, stream>>>(blocksums, nb, row_start, N, E, blockhist, nbp);
  b2c_rescan<<<nb, 256, 0, stream>>>(deg, blocksums, row_start, cursor, N);
  b3b5c_scatter<<<nb + (E + 255) / 256, 256, 0, stream>>>(
      rows, cols, cursor, colperm, E, deg, blockhist, row_order, N, nbp, nb);

  // dense feature transform (swapped-operand MFMA, direct stores)
  p1_wconv<<<(NH * FO * FI + 255) / 256, 256, 0, stream>>>(W, Wth);
  k1_v3<<<(N + BM - 1) / BM, 512, 0, stream>>>(x, Wth, a, Th, aw, N);

  // fused edge pipeline (heavy-first degree-sorted row assignment)
  k4_fused<<<(N + 15) / 16, 256, 0, stream>>>(row_start, colperm, row_order,
                                              aw, Th, b, out, N);
}

// Round 13
// 279.555 us; speedup vs baseline: 1.0646x; 1.0646x over previous
//
#include <hip/hip_runtime.h>
#include <hip/hip_bf16.h>
#include <hip/hip_fp16.h>

// SparseGAT forward. Swapped-operand fp16 MFMA feature transform (BM=64,
// direct register->global stores); CSR edge pipeline, 16-lane-group rows,
// degree-sorted heavy-first, per-chunk ASCENDING-COLUMN bitonic sort for
// L2 temporal locality on the Th gather.
// N=50000, FI=256, FO=64, H=8, E=800000, avg deg 16.
//
// Th [n][h*64+f] head-major fp16 (1KB/row).
// ws: Th[N*512]f16 | Wth[8*64*256]f16 | aw[N*8]f32 | deg[N] | blockhist[64*nbp]
//     | row_start[N+4] | cursor[N] | colperm[E] | blocksums[64] | row_order[N]

#define FI 256
#define FO 64
#define NH 8
#define FC 512
#define BM 64
#define NBIN 64

typedef _Float16 f16x8 __attribute__((ext_vector_type(8)));
typedef float f32x16 __attribute__((ext_vector_type(16)));
typedef float f32x8 __attribute__((ext_vector_type(8)));

// ---------------- P1: W[h][k][f] -> Wth[h][f][k] fp16 -----------------------
__global__ __launch_bounds__(256)
void p1_wconv(const float* __restrict__ W, _Float16* __restrict__ Wth) {
  int idx = blockIdx.x * 256 + threadIdx.x;   // h*64*256 + f*256 + k
  if (idx >= NH * FO * FI) return;
  int k = idx & (FI - 1);
  int f = (idx >> 8) & (FO - 1);
  int h = idx >> 14;
  Wth[idx] = (_Float16)W[((size_t)h * FI + k) * FO + f];
}

// ---------------- K1v4: swapped-operand MFMA, BM=64, direct stores ----------
// 512 threads = 8 waves; wave w = head w. mfma(W-frag, x-frag) -> D[f][node].
__global__ __launch_bounds__(512)
void k1_v4(const float* __restrict__ x, const _Float16* __restrict__ Wth,
           const float* __restrict__ a, _Float16* __restrict__ Th,
           float* __restrict__ aw, int N) {
  __shared__ _Float16 Xs[BM][136];   // 17.4 KB; +8 pad
  const int bm = blockIdx.x * BM;
  const int t = threadIdx.x;
  const int w = t >> 6;             // wave id = head
  const int lane = t & 63;
  const int l31 = lane & 31;
  const int hi = lane >> 5;
  const int kh = hi * 8;
  const _Float16* Wh = Wth + (size_t)w * (FO * FI);

  f32x16 acc[2][2];
  #pragma unroll
  for (int mr = 0; mr < 2; ++mr)
    #pragma unroll
    for (int wc = 0; wc < 2; ++wc) acc[mr][wc] = (f32x16)0.0f;

  #pragma unroll
  for (int k0 = 0; k0 < 2; ++k0) {
    if (k0) __syncthreads();
    // stage 64x128 fp16 chunk: 2048 float4, 4 per thread
    #pragma unroll
    for (int r = 0; r < 4; ++r) {
      int i = t + r * 512;          // 0..2047
      int row = i >> 5;             // 32 float4 per row
      int q = i & 31;
      float4 v = make_float4(0.f, 0.f, 0.f, 0.f);
      if (bm + row < N)
        v = reinterpret_cast<const float4*>(&x[(size_t)(bm + row) * FI + k0 * 128])[q];
      _Float16 o[4] = {(_Float16)v.x, (_Float16)v.y, (_Float16)v.z, (_Float16)v.w};
      *reinterpret_cast<uint2*>(&Xs[row][q * 4]) = *reinterpret_cast<uint2*>(o);
    }
    __syncthreads();
    #pragma unroll
    for (int kk = 0; kk < 8; ++kk) {
      f16x8 xf[2], wf[2];
      #pragma unroll
      for (int mr = 0; mr < 2; ++mr)
        xf[mr] = *reinterpret_cast<const f16x8*>(&Xs[mr * 32 + l31][kk * 16 + kh]);
      #pragma unroll
      for (int wc = 0; wc < 2; ++wc)
        wf[wc] = *reinterpret_cast<const f16x8*>(
            &Wh[(size_t)(wc * 32 + l31) * FI + k0 * 128 + kk * 16 + kh]);
      // SWAPPED: A=W-frag (i=f), B=x-frag (j=node) -> D[f][node]
      #pragma unroll
      for (int mr = 0; mr < 2; ++mr)
        #pragma unroll
        for (int wc = 0; wc < 2; ++wc)
          acc[mr][wc] =
              __builtin_amdgcn_mfma_f32_32x32x16_f16(wf[wc], xf[mr], acc[mr][wc], 0, 0, 0);
    }
  }

  // aw: per-lane dot over its 32 f, combine lane-halves with one shfl
  float s4[2] = {0.f, 0.f};
  #pragma unroll
  for (int wc = 0; wc < 2; ++wc)
    #pragma unroll
    for (int reg = 0; reg < 16; ++reg) {
      float av = a[w * FO + wc * 32 + (reg & 3) + 8 * (reg >> 2) + 4 * hi];
      #pragma unroll
      for (int mr = 0; mr < 2; ++mr)
        s4[mr] = fmaf(acc[mr][wc][reg], av, s4[mr]);
    }
  #pragma unroll
  for (int mr = 0; mr < 2; ++mr) {
    float s = s4[mr] + __shfl_xor(s4[mr], 32);
    int n = bm + mr * 32 + l31;
    if (hi == 0 && n < N) aw[(size_t)n * NH + w] = s;
  }

  // direct stores: per (mr,wc,quad g): 4 consecutive f -> 8B store
  #pragma unroll
  for (int mr = 0; mr < 2; ++mr) {
    int n = bm + mr * 32 + l31;
    if (n >= N) continue;
    _Float16* rowp = Th + (size_t)n * FC + w * FO;
    #pragma unroll
    for (int wc = 0; wc < 2; ++wc)
      #pragma unroll
      for (int g = 0; g < 4; ++g) {
        _Float16 o[4] = {(_Float16)acc[mr][wc][4 * g + 0],
                         (_Float16)acc[mr][wc][4 * g + 1],
                         (_Float16)acc[mr][wc][4 * g + 2],
                         (_Float16)acc[mr][wc][4 * g + 3]};
        *reinterpret_cast<uint2*>(&rowp[wc * 32 + 8 * g + 4 * hi]) =
            *reinterpret_cast<uint2*>(o);
      }
  }
}

// ---------------- B1: degree histogram --------------------------------------
__global__ __launch_bounds__(256)
void b1_hist(const int* __restrict__ rows, int* __restrict__ deg, int E) {
  int e = blockIdx.x * 256 + threadIdx.x;
  if (e < E) atomicAdd(&deg[rows[e]], 1);
}

// ---------------- B2a: per-block sums + per-block degree histogram ----------
__global__ __launch_bounds__(256)
void b2a_blocksum(const int* __restrict__ deg, int* __restrict__ blocksums,
                  int* __restrict__ blockhist, int N, int nbp) {
  __shared__ int red[256];
  __shared__ int hist[NBIN];
  const int t = threadIdx.x;
  const int base = blockIdx.x * 1024 + t * 4;
  if (t < NBIN) hist[t] = 0;
  int v[4]; int s = 0;
  #pragma unroll
  for (int j = 0; j < 4; ++j) { int i = base + j; v[j] = (i < N) ? deg[i] : 0; s += v[j]; }
  __syncthreads();                      // hist init visible
  #pragma unroll
  for (int j = 0; j < 4; ++j)
    if (base + j < N) atomicAdd(&hist[min(v[j], NBIN - 1)], 1);
  red[t] = s;
  __syncthreads();
  for (int off = 128; off; off >>= 1) {
    if (t < off) red[t] += red[t + off];
    __syncthreads();
  }
  if (t == 0) blocksums[blockIdx.x] = red[0];
  if (t < NBIN) blockhist[t * nbp + blockIdx.x] = hist[t];
}

// ---------------- B2b5b: fused single-wave scans (128 threads) --------------
__global__ __launch_bounds__(128)
void b2b5b_scan(int* __restrict__ blocksums, int nb,
                int* __restrict__ row_start, int N, int E,
                int* __restrict__ blockhist, int nbp) {
  const int w = threadIdx.x >> 6;
  const int lane = threadIdx.x & 63;
  if (w == 0) {
    int carry = 0;
    for (int base = 0; base < nb; base += 64) {
      int i = base + lane;
      int v = (i < nb) ? blocksums[i] : 0;
      int inc = v;
      #pragma unroll
      for (int off = 1; off < 64; off <<= 1) {
        int t = __shfl_up(inc, off);
        if (lane >= off) inc += t;
      }
      if (i < nb) blocksums[i] = inc - v + carry;  // exclusive
      carry += __shfl(inc, 63);
    }
    if (lane == 0) row_start[N] = E;
  } else {
    // lane handles bin (63 - lane): heavy-first global order
    int* rowp = blockhist + (size_t)(NBIN - 1 - lane) * nbp;
    int tot = 0;
    for (int c = 0; c < nbp / 4; ++c) {
      int4 v = reinterpret_cast<const int4*>(rowp)[c];
      tot += v.x + v.y + v.z + v.w;
    }
    int inc = tot;
    #pragma unroll
    for (int off = 1; off < 64; off <<= 1) {
      int t = __shfl_up(inc, off);
      if (lane >= off) inc += t;
    }
    int run = inc - tot;              // global base of this bin
    for (int c = 0; c < nbp / 4; ++c) {
      int4 v = reinterpret_cast<const int4*>(rowp)[c];
      int4 o;
      o.x = run; run += v.x;
      o.y = run; run += v.y;
      o.z = run; run += v.z;
      o.w = run; run += v.w;
      reinterpret_cast<int4*>(rowp)[c] = o;
    }
  }
}

// ---------------- B2c: per-block rescan -> row_start, cursor ----------------
__global__ __launch_bounds__(256)
void b2c_rescan(const int* __restrict__ deg, const int* __restrict__ blocksums,
                int* __restrict__ row_start, int* __restrict__ cursor, int N) {
  __shared__ int ts[256];
  const int t = threadIdx.x;
  const int base = blockIdx.x * 1024 + t * 4;
  int v[4]; int s = 0;
  #pragma unroll
  for (int j = 0; j < 4; ++j) { int i = base + j; v[j] = (i < N) ? deg[i] : 0; s += v[j]; }
  ts[t] = s;
  __syncthreads();
  for (int off = 1; off < 256; off <<= 1) {
    int add = (t >= off) ? ts[t - off] : 0;
    __syncthreads();
    ts[t] += add;
    __syncthreads();
  }
  int run = blocksums[blockIdx.x] + ts[t] - s;
  #pragma unroll
  for (int j = 0; j < 4; ++j) {
    int i = base + j;
    if (i < N) { row_start[i] = run; cursor[i] = run; run += v[j]; }
  }
}

// ---------------- B3+B5c fused: edge scatter + row-order scatter ------------
__global__ __launch_bounds__(256)
void b3b5c_scatter(const int* __restrict__ rows, const int* __restrict__ cols,
                   int* __restrict__ cursor, int* __restrict__ colperm, int E,
                   const int* __restrict__ deg, const int* __restrict__ blockhist,
                   int* __restrict__ row_order, int N, int nbp, int nb) {
  __shared__ int cur[NBIN];
  const int t = threadIdx.x;
  if ((int)blockIdx.x < nb) {
    if (t < NBIN) cur[t] = blockhist[t * nbp + blockIdx.x];
    __syncthreads();
    const int base = blockIdx.x * 1024 + t * 4;
    #pragma unroll
    for (int j = 0; j < 4; ++j) {
      int i = base + j;
      if (i < N) {
        int pos = atomicAdd(&cur[min(deg[i], NBIN - 1)], 1);
        row_order[pos] = i;
      }
    }
  } else {
    int e = (blockIdx.x - nb) * 256 + t;
    if (e < E) {
      int pos = atomicAdd(&cursor[rows[e]], 1);
      colperm[pos] = cols[e];
    }
  }
}

// ---------------- K4: fused softmax + aggregation ---------------------------
// 16-lane group per row (degree-sorted heavy-first). Each 16-edge chunk's
// columns are bitonic-sorted ASCENDING in-register: concurrent groups sweep
// the column space together -> Th gather gains L2 temporal locality.
__global__ __launch_bounds__(256)
void k4_fused(const int* __restrict__ row_start, const int* __restrict__ colperm,
              const int* __restrict__ row_order,
              const float* __restrict__ aw, const _Float16* __restrict__ Th,
              const float* __restrict__ b, float* __restrict__ out, int N) {
  const int lane16 = threadIdx.x & 15;
  const int gbase  = threadIdx.x & 48;       // group base lane within wave
  const int hi8    = lane16 >> 3;            // head parity of this lane
  const int ri = blockIdx.x * 16 + (threadIdx.x >> 4);
  if (ri >= N) return;
  const int r = row_order[ri];

  const int s0 = row_start[r], s1 = row_start[r + 1];
  f32x8 awr = *reinterpret_cast<const f32x8*>(&aw[(size_t)r * NH]);

  float facc[4][8] = {};
  float dacc[NH] = {};

  for (int base = s0; base < s1; base += 16) {
    const int mm = min(16, s1 - base);
    const bool valid = lane16 < mm;

    // load + ascending bitonic sort of this chunk's columns (invalid -> MAX)
    int key = valid ? colperm[base + lane16] : 0x7fffffff;
    #pragma unroll
    for (int k = 2; k <= 16; k <<= 1)
      #pragma unroll
      for (int j = k >> 1; j > 0; j >>= 1) {
        int other = __shfl_xor(key, j);
        bool take_min = (((lane16 & k) == 0) == ((lane16 & j) == 0));
        key = take_min ? min(key, other) : max(key, other);
      }
    int c_l = valid ? key : 0;   // sorted: lanes < mm hold real cols ascending

    f32x8 awc = *reinterpret_cast<const f32x8*>(&aw[(size_t)c_l * NH]);
    float ex[NH];
    int pkv[4];
    #pragma unroll
    for (int h = 0; h < NH; ++h) {
      float s = awr[h] + awc[h];
      float lr = s > 0.f ? s : 0.2f * s;
      ex[h] = valid ? __expf(lr) : 0.f;
      dacc[h] += ex[h];
    }
    #pragma unroll
    for (int q = 0; q < 4; ++q) {
      __half2 h2 = __floats2half2_rn(ex[2 * q], ex[2 * q + 1]);
      pkv[q] = *reinterpret_cast<int*>(&h2);
    }

    // serial gather in ascending-column order
    for (int j = 0; j < mm; ++j) {
      int cj = __shfl(c_l, gbase + j);
      const _Float16* tp = Th + (size_t)cj * FC + lane16 * 8;
      f16x8 tv0 = *reinterpret_cast<const f16x8*>(tp);
      f16x8 tv1 = *reinterpret_cast<const f16x8*>(tp + 128);
      f16x8 tv2 = *reinterpret_cast<const f16x8*>(tp + 256);
      f16x8 tv3 = *reinterpret_cast<const f16x8*>(tp + 384);
      float eq[4];
      #pragma unroll
      for (int q = 0; q < 4; ++q) {
        int p = __shfl(pkv[q], gbase + j);
        float2 f2 = __half22float2(*reinterpret_cast<__half2*>(&p));
        eq[q] = hi8 ? f2.y : f2.x;
      }
      #pragma unroll
      for (int e = 0; e < 8; ++e) {
        facc[0][e] = fmaf(eq[0], (float)tv0[e], facc[0][e]);
        facc[1][e] = fmaf(eq[1], (float)tv1[e], facc[1][e]);
        facc[2][e] = fmaf(eq[2], (float)tv2[e], facc[2][e]);
        facc[3][e] = fmaf(eq[3], (float)tv3[e], facc[3][e]);
      }
    }
  }

  #pragma unroll
  for (int h = 0; h < NH; ++h) {
    #pragma unroll
    for (int off = 1; off < 16; off <<= 1)
      dacc[h] += __shfl_xor(dacc[h], off);
  }
  float rden[NH];
  #pragma unroll
  for (int h = 0; h < NH; ++h) rden[h] = dacc[h] > 0.f ? 1.0f / dacc[h] : 0.f;

  float s[8] = {};
  #pragma unroll
  for (int q = 0; q < 4; ++q) {
    float rd = hi8 ? rden[2 * q + 1] : rden[2 * q];
    #pragma unroll
    for (int e = 0; e < 8; ++e) s[e] = fmaf(facc[q][e], rd, s[e]);
  }
  #pragma unroll
  for (int e = 0; e < 8; ++e) s[e] += __shfl_xor(s[e], 8);

  if (lane16 < 8) {
    #pragma unroll
    for (int e = 0; e < 8; ++e) {
      const int f = lane16 * 8 + e;
      float sb = 0.f;
      #pragma unroll
      for (int h = 0; h < NH; ++h) sb += b[h * FO + f];
      float v = (s[e] + sb) * 0.125f;
      out[(size_t)r * FO + f] = v > 0.f ? v : 0.f;
    }
  }
}

extern "C" void kernel_launch(void* const* d_in, const int* in_sizes, int n_in,
                              void* d_out, int out_size, void* d_ws, size_t ws_size,
                              hipStream_t stream) {
  const float* x    = (const float*)d_in[0];
  const float* W    = (const float*)d_in[1];
  const float* a    = (const float*)d_in[2];
  const float* b    = (const float*)d_in[3];
  const int*   rows = (const int*)d_in[4];
  const int*   cols = (const int*)d_in[5];
  const int N = in_sizes[0] / FI;
  const int E = in_sizes[4];

  const int nb  = (N + 1023) / 1024;        // 1024-row blocks
  const int nbp = ((nb + 3) / 4) * 4;       // padded for int4

  char* p = (char*)d_ws;
  _Float16* Th       = (_Float16*)p;  p += (size_t)N * FC * sizeof(_Float16);
  _Float16* Wth      = (_Float16*)p;  p += (size_t)NH * FO * FI * sizeof(_Float16);
  float*    aw       = (float*)p;     p += (size_t)N * NH * sizeof(float);
  int*      deg      = (int*)p;       p += (size_t)N * sizeof(int);
  int*      blockhist= (int*)p;       p += (size_t)NBIN * nbp * sizeof(int);
  int*      row_start= (int*)p;       p += (size_t)(N + 4) * sizeof(int);
  int*      cursor   = (int*)p;       p += (size_t)N * sizeof(int);
  int*      colperm  = (int*)p;       p += (size_t)E * sizeof(int);
  int*      blocksums= (int*)p;       p += 64 * sizeof(int);
  int*      row_order= (int*)p;       p += (size_t)N * sizeof(int);
  float*    out = (float*)d_out;

  // CSR build + degree sort (deg and blockhist adjacent: one memset)
  hipMemsetAsync(deg, 0, ((size_t)N + (size_t)NBIN * nbp) * sizeof(int), stream);
  b1_hist<<<(E + 255) / 256, 256, 0, stream>>>(rows, deg, E);
  b2a_blocksum<<<nb, 256, 0, stream>>>(deg, blocksums, blockhist, N, nbp);
  b2b5b_scan<<<1, 128, 0, stream>>>(blocksums, nb, row_start, N, E, blockhist, nbp);
  b2c_rescan<<<nb, 256, 0, stream>>>(deg, blocksums, row_start, cursor, N);
  b3b5c_scatter<<<nb + (E + 255) / 256, 256, 0, stream>>>(
      rows, cols, cursor, colperm, E, deg, blockhist, row_order, N, nbp, nb);

  // dense feature transform (swapped-operand MFMA, BM=64, direct stores)
  p1_wconv<<<(NH * FO * FI + 255) / 256, 256, 0, stream>>>(W, Wth);
  k1_v4<<<(N + BM - 1) / BM, 512, 0, stream>>>(x, Wth, a, Th, aw, N);

  // fused edge pipeline (heavy-first, ascending-column chunks)
  k4_fused<<<(N + 15) / 16, 256, 0, stream>>>(row_start, colperm, row_order,
                                              aw, Th, b, out, N);
}

// Round 14
// 253.747 us; speedup vs baseline: 1.1729x; 1.1017x over previous
//
#include <hip/hip_runtime.h>
#include <hip/hip_bf16.h>
#include <hip/hip_fp16.h>

// SparseGAT forward. Swapped-operand fp16 MFMA feature transform fused with
// the edge histogram (block-split overlap); CSR edge pipeline, 16-lane-group
// rows, degree-sorted heavy-first, ascending-column chunks.
// N=50000, FI=256, FO=64, H=8, E=800000, avg deg 16. 7 dispatches.
//
// Th [n][h*64+f] head-major fp16 (1KB/row).
// ws: Th[N*512]f16 | Wth[8*64*256]f16 | aw[N*8]f32 | deg[N] | blockhist[64*nbp]
//     | row_start[N+4] | cursor[N] | colperm[E] | blocksums[64] | row_order[N]

#define FI 256
#define FO 64
#define NH 8
#define FC 512
#define BM 64
#define NBIN 64

typedef _Float16 f16x8 __attribute__((ext_vector_type(8)));
typedef float f32x16 __attribute__((ext_vector_type(16)));
typedef float f32x8 __attribute__((ext_vector_type(8)));

// ---------------- PREP: zero deg+blockhist  +  W -> Wth fp16 ----------------
// blocks [0, zb): int4 zeroing of deg..blockhist (contiguous).
// blocks [zb, zb+pb): p1 transpose-convert W.
__global__ __launch_bounds__(256)
void prep(const float* __restrict__ W, _Float16* __restrict__ Wth,
          int* __restrict__ zbase, int zints, int zb) {
  const int t = threadIdx.x;
  if ((int)blockIdx.x < zb) {
    int i = blockIdx.x * 256 + t;          // int4 index
    if (i * 4 < zints)
      reinterpret_cast<int4*>(zbase)[i] = make_int4(0, 0, 0, 0);
  } else {
    int idx = (blockIdx.x - zb) * 256 + t; // h*64*256 + f*256 + k
    if (idx < NH * FO * FI) {
      int k = idx & (FI - 1);
      int f = (idx >> 8) & (FO - 1);
      int h = idx >> 14;
      Wth[idx] = (_Float16)W[((size_t)h * FI + k) * FO + f];
    }
  }
}

// ---------------- K1B1: fused k1_v4 MFMA + b1 edge histogram ----------------
// blocks [0, kb): k1_v4 (swapped-operand MFMA, BM=64, direct stores).
// blocks [kb, ..): b1 degree histogram (512 edges per block).
__global__ __launch_bounds__(512)
void k1b1(const float* __restrict__ x, const _Float16* __restrict__ Wth,
          const float* __restrict__ a, _Float16* __restrict__ Th,
          float* __restrict__ aw, int N, int kb,
          const int* __restrict__ rows, int* __restrict__ deg, int E) {
  if ((int)blockIdx.x >= kb) {
    int e = (blockIdx.x - kb) * 512 + threadIdx.x;
    if (e < E) atomicAdd(&deg[rows[e]], 1);
    return;
  }

  __shared__ _Float16 Xs[BM][136];   // 17.4 KB; +8 pad
  const int bm = blockIdx.x * BM;
  const int t = threadIdx.x;
  const int w = t >> 6;             // wave id = head
  const int lane = t & 63;
  const int l31 = lane & 31;
  const int hi = lane >> 5;
  const int kh = hi * 8;
  const _Float16* Wh = Wth + (size_t)w * (FO * FI);

  f32x16 acc[2][2];
  #pragma unroll
  for (int mr = 0; mr < 2; ++mr)
    #pragma unroll
    for (int wc = 0; wc < 2; ++wc) acc[mr][wc] = (f32x16)0.0f;

  #pragma unroll
  for (int k0 = 0; k0 < 2; ++k0) {
    if (k0) __syncthreads();
    #pragma unroll
    for (int r = 0; r < 4; ++r) {
      int i = t + r * 512;          // 0..2047
      int row = i >> 5;             // 32 float4 per row
      int q = i & 31;
      float4 v = make_float4(0.f, 0.f, 0.f, 0.f);
      if (bm + row < N)
        v = reinterpret_cast<const float4*>(&x[(size_t)(bm + row) * FI + k0 * 128])[q];
      _Float16 o[4] = {(_Float16)v.x, (_Float16)v.y, (_Float16)v.z, (_Float16)v.w};
      *reinterpret_cast<uint2*>(&Xs[row][q * 4]) = *reinterpret_cast<uint2*>(o);
    }
    __syncthreads();
    #pragma unroll
    for (int kk = 0; kk < 8; ++kk) {
      f16x8 xf[2], wf[2];
      #pragma unroll
      for (int mr = 0; mr < 2; ++mr)
        xf[mr] = *reinterpret_cast<const f16x8*>(&Xs[mr * 32 + l31][kk * 16 + kh]);
      #pragma unroll
      for (int wc = 0; wc < 2; ++wc)
        wf[wc] = *reinterpret_cast<const f16x8*>(
            &Wh[(size_t)(wc * 32 + l31) * FI + k0 * 128 + kk * 16 + kh]);
      // SWAPPED: A=W-frag (i=f), B=x-frag (j=node) -> D[f][node]
      #pragma unroll
      for (int mr = 0; mr < 2; ++mr)
        #pragma unroll
        for (int wc = 0; wc < 2; ++wc)
          acc[mr][wc] =
              __builtin_amdgcn_mfma_f32_32x32x16_f16(wf[wc], xf[mr], acc[mr][wc], 0, 0, 0);
    }
  }

  // aw: per-lane dot over its 32 f, combine lane-halves with one shfl
  float s4[2] = {0.f, 0.f};
  #pragma unroll
  for (int wc = 0; wc < 2; ++wc)
    #pragma unroll
    for (int reg = 0; reg < 16; ++reg) {
      float av = a[w * FO + wc * 32 + (reg & 3) + 8 * (reg >> 2) + 4 * hi];
      #pragma unroll
      for (int mr = 0; mr < 2; ++mr)
        s4[mr] = fmaf(acc[mr][wc][reg], av, s4[mr]);
    }
  #pragma unroll
  for (int mr = 0; mr < 2; ++mr) {
    float s = s4[mr] + __shfl_xor(s4[mr], 32);
    int n = bm + mr * 32 + l31;
    if (hi == 0 && n < N) aw[(size_t)n * NH + w] = s;
  }

  // direct stores: per (mr,wc,quad g): 4 consecutive f -> 8B store
  #pragma unroll
  for (int mr = 0; mr < 2; ++mr) {
    int n = bm + mr * 32 + l31;
    if (n >= N) continue;
    _Float16* rowp = Th + (size_t)n * FC + w * FO;
    #pragma unroll
    for (int wc = 0; wc < 2; ++wc)
      #pragma unroll
      for (int g = 0; g < 4; ++g) {
        _Float16 o[4] = {(_Float16)acc[mr][wc][4 * g + 0],
                         (_Float16)acc[mr][wc][4 * g + 1],
                         (_Float16)acc[mr][wc][4 * g + 2],
                         (_Float16)acc[mr][wc][4 * g + 3]};
        *reinterpret_cast<uint2*>(&rowp[wc * 32 + 8 * g + 4 * hi]) =
            *reinterpret_cast<uint2*>(o);
      }
  }
}

// ---------------- B2a: per-block sums + per-block degree histogram ----------
__global__ __launch_bounds__(256)
void b2a_blocksum(const int* __restrict__ deg, int* __restrict__ blocksums,
                  int* __restrict__ blockhist, int N, int nbp) {
  __shared__ int red[256];
  __shared__ int hist[NBIN];
  const int t = threadIdx.x;
  const int base = blockIdx.x * 1024 + t * 4;
  if (t < NBIN) hist[t] = 0;
  int v[4]; int s = 0;
  #pragma unroll
  for (int j = 0; j < 4; ++j) { int i = base + j; v[j] = (i < N) ? deg[i] : 0; s += v[j]; }
  __syncthreads();                      // hist init visible
  #pragma unroll
  for (int j = 0; j < 4; ++j)
    if (base + j < N) atomicAdd(&hist[min(v[j], NBIN - 1)], 1);
  red[t] = s;
  __syncthreads();
  for (int off = 128; off; off >>= 1) {
    if (t < off) red[t] += red[t + off];
    __syncthreads();
  }
  if (t == 0) blocksums[blockIdx.x] = red[0];
  if (t < NBIN) blockhist[t * nbp + blockIdx.x] = hist[t];
}

// ---------------- B2b5b: fused single-wave scans (128 threads) --------------
__global__ __launch_bounds__(128)
void b2b5b_scan(int* __restrict__ blocksums, int nb,
                int* __restrict__ row_start, int N, int E,
                int* __restrict__ blockhist, int nbp) {
  const int w = threadIdx.x >> 6;
  const int lane = threadIdx.x & 63;
  if (w == 0) {
    int carry = 0;
    for (int base = 0; base < nb; base += 64) {
      int i = base + lane;
      int v = (i < nb) ? blocksums[i] : 0;
      int inc = v;
      #pragma unroll
      for (int off = 1; off < 64; off <<= 1) {
        int t = __shfl_up(inc, off);
        if (lane >= off) inc += t;
      }
      if (i < nb) blocksums[i] = inc - v + carry;  // exclusive
      carry += __shfl(inc, 63);
    }
    if (lane == 0) row_start[N] = E;
  } else {
    // lane handles bin (63 - lane): heavy-first global order
    int* rowp = blockhist + (size_t)(NBIN - 1 - lane) * nbp;
    int tot = 0;
    for (int c = 0; c < nbp / 4; ++c) {
      int4 v = reinterpret_cast<const int4*>(rowp)[c];
      tot += v.x + v.y + v.z + v.w;
    }
    int inc = tot;
    #pragma unroll
    for (int off = 1; off < 64; off <<= 1) {
      int t = __shfl_up(inc, off);
      if (lane >= off) inc += t;
    }
    int run = inc - tot;              // global base of this bin
    for (int c = 0; c < nbp / 4; ++c) {
      int4 v = reinterpret_cast<const int4*>(rowp)[c];
      int4 o;
      o.x = run; run += v.x;
      o.y = run; run += v.y;
      o.z = run; run += v.z;
      o.w = run; run += v.w;
      reinterpret_cast<int4*>(rowp)[c] = o;
    }
  }
}

// ---------------- B2c: per-block rescan -> row_start, cursor ----------------
__global__ __launch_bounds__(256)
void b2c_rescan(const int* __restrict__ deg, const int* __restrict__ blocksums,
                int* __restrict__ row_start, int* __restrict__ cursor, int N) {
  __shared__ int ts[256];
  const int t = threadIdx.x;
  const int base = blockIdx.x * 1024 + t * 4;
  int v[4]; int s = 0;
  #pragma unroll
  for (int j = 0; j < 4; ++j) { int i = base + j; v[j] = (i < N) ? deg[i] : 0; s += v[j]; }
  ts[t] = s;
  __syncthreads();
  for (int off = 1; off < 256; off <<= 1) {
    int add = (t >= off) ? ts[t - off] : 0;
    __syncthreads();
    ts[t] += add;
    __syncthreads();
  }
  int run = blocksums[blockIdx.x] + ts[t] - s;
  #pragma unroll
  for (int j = 0; j < 4; ++j) {
    int i = base + j;
    if (i < N) { row_start[i] = run; cursor[i] = run; run += v[j]; }
  }
}

// ---------------- B3+B5c fused: edge scatter + row-order scatter ------------
__global__ __launch_bounds__(256)
void b3b5c_scatter(const int* __restrict__ rows, const int* __restrict__ cols,
                   int* __restrict__ cursor, int* __restrict__ colperm, int E,
                   const int* __restrict__ deg, const int* __restrict__ blockhist,
                   int* __restrict__ row_order, int N, int nbp, int nb) {
  __shared__ int cur[NBIN];
  const int t = threadIdx.x;
  if ((int)blockIdx.x < nb) {
    if (t < NBIN) cur[t] = blockhist[t * nbp + blockIdx.x];
    __syncthreads();
    const int base = blockIdx.x * 1024 + t * 4;
    #pragma unroll
    for (int j = 0; j < 4; ++j) {
      int i = base + j;
      if (i < N) {
        int pos = atomicAdd(&cur[min(deg[i], NBIN - 1)], 1);
        row_order[pos] = i;
      }
    }
  } else {
    int e = (blockIdx.x - nb) * 256 + t;
    if (e < E) {
      int pos = atomicAdd(&cursor[rows[e]], 1);
      colperm[pos] = cols[e];
    }
  }
}

// ---------------- K4: fused softmax + aggregation ---------------------------
// 16-lane group per row (degree-sorted heavy-first); ascending-column chunks.
__global__ __launch_bounds__(256)
void k4_fused(const int* __restrict__ row_start, const int* __restrict__ colperm,
              const int* __restrict__ row_order,
              const float* __restrict__ aw, const _Float16* __restrict__ Th,
              const float* __restrict__ b, float* __restrict__ out, int N) {
  const int lane16 = threadIdx.x & 15;
  const int gbase  = threadIdx.x & 48;       // group base lane within wave
  const int hi8    = lane16 >> 3;            // head parity of this lane
  const int ri = blockIdx.x * 16 + (threadIdx.x >> 4);
  if (ri >= N) return;
  const int r = row_order[ri];

  const int s0 = row_start[r], s1 = row_start[r + 1];
  f32x8 awr = *reinterpret_cast<const f32x8*>(&aw[(size_t)r * NH]);

  float facc[4][8] = {};
  float dacc[NH] = {};

  for (int base = s0; base < s1; base += 16) {
    const int mm = min(16, s1 - base);
    const bool valid = lane16 < mm;

    // load + ascending bitonic sort of this chunk's columns (invalid -> MAX)
    int key = valid ? colperm[base + lane16] : 0x7fffffff;
    #pragma unroll
    for (int k = 2; k <= 16; k <<= 1)
      #pragma unroll
      for (int j = k >> 1; j > 0; j >>= 1) {
        int other = __shfl_xor(key, j);
        bool take_min = (((lane16 & k) == 0) == ((lane16 & j) == 0));
        key = take_min ? min(key, other) : max(key, other);
      }
    int c_l = valid ? key : 0;   // sorted: lanes < mm hold real cols ascending

    f32x8 awc = *reinterpret_cast<const f32x8*>(&aw[(size_t)c_l * NH]);
    float ex[NH];
    int pkv[4];
    #pragma unroll
    for (int h = 0; h < NH; ++h) {
      float s = awr[h] + awc[h];
      float lr = s > 0.f ? s : 0.2f * s;
      ex[h] = valid ? __expf(lr) : 0.f;
      dacc[h] += ex[h];
    }
    #pragma unroll
    for (int q = 0; q < 4; ++q) {
      __half2 h2 = __floats2half2_rn(ex[2 * q], ex[2 * q + 1]);
      pkv[q] = *reinterpret_cast<int*>(&h2);
    }

    // serial gather in ascending-column order
    for (int j = 0; j < mm; ++j) {
      int cj = __shfl(c_l, gbase + j);
      const _Float16* tp = Th + (size_t)cj * FC + lane16 * 8;
      f16x8 tv0 = *reinterpret_cast<const f16x8*>(tp);
      f16x8 tv1 = *reinterpret_cast<const f16x8*>(tp + 128);
      f16x8 tv2 = *reinterpret_cast<const f16x8*>(tp + 256);
      f16x8 tv3 = *reinterpret_cast<const f16x8*>(tp + 384);
      float eq[4];
      #pragma unroll
      for (int q = 0; q < 4; ++q) {
        int p = __shfl(pkv[q], gbase + j);
        float2 f2 = __half22float2(*reinterpret_cast<__half2*>(&p));
        eq[q] = hi8 ? f2.y : f2.x;
      }
      #pragma unroll
      for (int e = 0; e < 8; ++e) {
        facc[0][e] = fmaf(eq[0], (float)tv0[e], facc[0][e]);
        facc[1][e] = fmaf(eq[1], (float)tv1[e], facc[1][e]);
        facc[2][e] = fmaf(eq[2], (float)tv2[e], facc[2][e]);
        facc[3][e] = fmaf(eq[3], (float)tv3[e], facc[3][e]);
      }
    }
  }

  #pragma unroll
  for (int h = 0; h < NH; ++h) {
    #pragma unroll
    for (int off = 1; off < 16; off <<= 1)
      dacc[h] += __shfl_xor(dacc[h], off);
  }
  float rden[NH];
  #pragma unroll
  for (int h = 0; h < NH; ++h) rden[h] = dacc[h] > 0.f ? 1.0f / dacc[h] : 0.f;

  float s[8] = {};
  #pragma unroll
  for (int q = 0; q < 4; ++q) {
    float rd = hi8 ? rden[2 * q + 1] : rden[2 * q];
    #pragma unroll
    for (int e = 0; e < 8; ++e) s[e] = fmaf(facc[q][e], rd, s[e]);
  }
  #pragma unroll
  for (int e = 0; e < 8; ++e) s[e] += __shfl_xor(s[e], 8);

  if (lane16 < 8) {
    #pragma unroll
    for (int e = 0; e < 8; ++e) {
      const int f = lane16 * 8 + e;
      float sb = 0.f;
      #pragma unroll
      for (int h = 0; h < NH; ++h) sb += b[h * FO + f];
      float v = (s[e] + sb) * 0.125f;
      out[(size_t)r * FO + f] = v > 0.f ? v : 0.f;
    }
  }
}

extern "C" void kernel_launch(void* const* d_in, const int* in_sizes, int n_in,
                              void* d_out, int out_size, void* d_ws, size_t ws_size,
                              hipStream_t stream) {
  const float* x    = (const float*)d_in[0];
  const float* W    = (const float*)d_in[1];
  const float* a    = (const float*)d_in[2];
  const float* b    = (const float*)d_in[3];
  const int*   rows = (const int*)d_in[4];
  const int*   cols = (const int*)d_in[5];
  const int N = in_sizes[0] / FI;
  const int E = in_sizes[4];

  const int nb  = (N + 1023) / 1024;        // 1024-row blocks
  const int nbp = ((nb + 3) / 4) * 4;       // padded for int4

  char* p = (char*)d_ws;
  _Float16* Th       = (_Float16*)p;  p += (size_t)N * FC * sizeof(_Float16);
  _Float16* Wth      = (_Float16*)p;  p += (size_t)NH * FO * FI * sizeof(_Float16);
  float*    aw       = (float*)p;     p += (size_t)N * NH * sizeof(float);
  int*      deg      = (int*)p;       p += (size_t)N * sizeof(int);
  int*      blockhist= (int*)p;       p += (size_t)NBIN * nbp * sizeof(int);
  int*      row_start= (int*)p;       p += (size_t)(N + 4) * sizeof(int);
  int*      cursor   = (int*)p;       p += (size_t)N * sizeof(int);
  int*      colperm  = (int*)p;       p += (size_t)E * sizeof(int);
  int*      blocksums= (int*)p;       p += 64 * sizeof(int);
  int*      row_order= (int*)p;       p += (size_t)N * sizeof(int);
  float*    out = (float*)d_out;

  // prep: zero deg+blockhist (contiguous) + W transpose-convert
  const int zints = N + NBIN * nbp;                 // ints to zero
  const int zb = (zints / 4 + 255) / 256;           // int4-zero blocks
  const int pb = (NH * FO * FI + 255) / 256;        // p1 blocks
  prep<<<zb + pb, 256, 0, stream>>>(W, Wth, deg, zints, zb);

  // fused MFMA transform + edge histogram (independent, overlapped)
  const int kb = (N + BM - 1) / BM;                 // k1 blocks
  const int hb = (E + 511) / 512;                   // b1 blocks
  k1b1<<<kb + hb, 512, 0, stream>>>(x, Wth, a, Th, aw, N, kb, rows, deg, E);

  // CSR scans + scatters + degree sort
  b2a_blocksum<<<nb, 256, 0, stream>>>(deg, blocksums, blockhist, N, nbp);
  b2b5b_scan<<<1, 128, 0, stream>>>(blocksums, nb, row_start, N, E, blockhist, nbp);
  b2c_rescan<<<nb, 256, 0, stream>>>(deg, blocksums, row_start, cursor, N);
  b3b5c_scatter<<<nb + (E + 255) / 256, 256, 0, stream>>>(
      rows, cols, cursor, colperm, E, deg, blockhist, row_order, N, nbp, nb);

  // fused edge pipeline (heavy-first, ascending-column chunks)
  k4_fused<<<(N + 15) / 16, 256, 0, stream>>>(row_start, colperm, row_order,
                                              aw, Th, b, out, N);
}